// Round 6
// baseline (194.480 us; speedup 1.0000x reference)
//
#include <hip/hip_runtime.h>
#include <math.h>

#define BB 8
#define TT 2048
#define EE 1024
#define DD 128

typedef _Float16 f16x8 __attribute__((ext_vector_type(8)));
typedef _Float16 f16x4 __attribute__((ext_vector_type(4)));
typedef float    f32x4 __attribute__((ext_vector_type(4)));
typedef float    f32x16 __attribute__((ext_vector_type(16)));

// scale (128^-0.5) * log2(e): folded into q so softmax runs in exp2 domain
#define QSCALE 0.12752406f

// ---------------------------------------------------------------------------
// Fragment layouts (32x32x16 MFMA, m74/m101 verified, used since R5):
//   A[m = lane&31][k = (lane>>5)*8 + j]   (f16x8 per lane)
//   B[k = (lane>>5)*8 + j][n = lane&31]
//   C/D row = (rg&3) + 8*(rg>>2) + 4*(lane>>5), col = lane&31
// Pre-swizzled global arrays store one 64-lane fragment contiguously:
//   frag_id * 512 + lane*8 + j  -> every frag load = one coalesced 1KB read.
// ---------------------------------------------------------------------------

// Kernel 0: Wb[(kc*12 + ns)*512 + lane*8 + j] = W[k = kc*16+(lane>>5)*8+j]
//           [n = ns*32+(lane&31)], n spans q|k|v (0..383).
__global__ __launch_bounds__(256)
void wt_prep_kernel(const float* __restrict__ Wq,
                    const float* __restrict__ Wk,
                    const float* __restrict__ Wv,
                    _Float16* __restrict__ Wb)
{
    int gid = blockIdx.x * 256 + threadIdx.x;   // 0..49151
    int kc  = gid / 768;                        // 0..63
    int rem = gid - kc * 768;
    int ns  = rem >> 6;                         // 0..11
    int ln  = rem & 63;
    int n   = ns * 32 + (ln & 31);
    int k0  = kc * 16 + (ln >> 5) * 8;
    const float* __restrict__ W = (n < 128) ? Wq : (n < 256) ? Wk : Wv;
    int nl = n & 127;
    f16x8 w;
#pragma unroll
    for (int j = 0; j < 8; j++)
        w[j] = (_Float16)W[(size_t)(k0 + j) * DD + nl];
    *(f16x8*)&Wb[(size_t)gid * 8] = w;
}

// ---------------------------------------------------------------------------
// Kernel 1: fused QKV projection — BARRIER-FREE main loop.
// M-tile 64, N=384, grid 256 (1 block/CU), 512 thr = 8 waves
// (wave_m{0,1} x wave_n{0..3}; wave = 1 m-subtile x 3 n-subtiles).
// A-frags straight from x (f32, one 64B line per k-chunk per row, cvt->f16);
// B-frags from pre-swizzled Wb (coalesced, L2-resident).
// Epilogue: RoPE in C-layout, then Out-LDS round-trip into frag layouts:
//   Qb/Ka[((b*64+qs)*8+kc)*512 + lane*8]  (B-frag for S^T / A-frag for K)
//   Va[((b*128+kcg)*4+ds)*512 + lane*8]   (V^T A-frag: m=d, k=key)
// ---------------------------------------------------------------------------
__global__ __launch_bounds__(512)
void proj_rope_kernel(const float* __restrict__ x,
                      const _Float16* __restrict__ Wb,
                      _Float16* __restrict__ Qb,
                      _Float16* __restrict__ Ka,
                      _Float16* __restrict__ Va)
{
    const int r0   = blockIdx.x * 64;       // 64 | 2048: never straddles batch
    const int tid  = threadIdx.x;
    const int wave = tid >> 6;
    const int lane = tid & 63;
    const int half = lane >> 5;
    const int col  = lane & 31;
    const int wave_m = wave & 1;
    const int wave_n = wave >> 1;

    __shared__ _Float16 Out[64][136];       // epilogue transpose buffer only

    f32x16 acc[3];
#pragma unroll
    for (int s = 0; s < 3; s++) acc[s] = (f32x16)0.f;

    const float* __restrict__ xp =
        &x[(size_t)(r0 + wave_m * 32 + col) * EE + half * 8];

#pragma unroll 4
    for (int kc = 0; kc < 64; kc++) {
        float4 a0 = *(const float4*)(xp + kc * 16);
        float4 a1 = *(const float4*)(xp + kc * 16 + 4);
        f16x8 afr = { (_Float16)a0.x, (_Float16)a0.y, (_Float16)a0.z, (_Float16)a0.w,
                      (_Float16)a1.x, (_Float16)a1.y, (_Float16)a1.z, (_Float16)a1.w };
#pragma unroll
        for (int s = 0; s < 3; s++) {
            f16x8 bfr = *(const f16x8*)&Wb[((size_t)kc * 12 + wave_n * 3 + s) * 512 + lane * 8];
            acc[s] = __builtin_amdgcn_mfma_f32_32x32x16_f16(afr, bfr, acc[s], 0, 0, 0);
        }
    }

    // ---- epilogue: RoPE + frag-layout stores via Out round-trip ----
    const int bidx = r0 >> 11;
    const int t0   = r0 & (TT - 1);

    for (int p = 0; p < 3; p++) {
        __syncthreads();
#pragma unroll
        for (int s = 0; s < 3; s++) {
            int gs = wave_n * 3 + s;        // 0..11 global 32-col subtile
            if ((gs >> 2) != p) continue;
            int dcol = (gs & 3) * 32 + col; // 0..127 within matrix p
            float f = 0.f;
            if (p < 2)
                f = __powf(10000.0f, -(float)(dcol & ~1) * (1.0f / 128.0f));
#pragma unroll
            for (int rg = 0; rg < 16; rg++) {
                int mrow = wave_m * 32 + (rg & 3) + 8 * (rg >> 2) + 4 * half;
                float av = acc[s][rg];
                float res;
                if (p < 2) {
                    float ap = __shfl_xor(av, 1);   // RoPE pair partner (dcol^1)
                    float sa, ca;
                    __sincosf((float)(t0 + mrow) * f, &sa, &ca);
                    res = av * ca + ap * ((dcol & 1) ? sa : -sa);
                    if (p == 0) res *= QSCALE;
                } else {
                    res = av;
                }
                Out[mrow][dcol] = (_Float16)res;
            }
        }
        __syncthreads();
        if (p < 2) {
            _Float16* __restrict__ dst = (p == 0) ? Qb : Ka;
#pragma unroll
            for (int jj = 0; jj < 2; jj++) {
                int cid = tid + 512 * jj;   // 0..1023 = 2 subtiles x 8 kc x 64 lanes
                int sl = cid >> 9, kc = (cid >> 6) & 7, ln = cid & 63;
                f16x8 v8 = *(f16x8*)&Out[sl * 32 + (ln & 31)][kc * 16 + (ln >> 5) * 8];
                size_t ga = ((((size_t)bidx * 64 + (t0 >> 5) + sl) * 8 + kc) * 64 + ln) * 8;
                *(f16x8*)&dst[ga] = v8;
            }
        } else {
#pragma unroll
            for (int jj = 0; jj < 2; jj++) {
                int cid = tid + 512 * jj;   // 0..1023 = 4 key-chunks x 4 ds x 64 lanes
                int kcl = cid >> 8, ds = (cid >> 6) & 3, ln = cid & 63;
                f16x8 vv;
#pragma unroll
                for (int e = 0; e < 8; e++)
                    vv[e] = Out[kcl * 16 + (ln >> 5) * 8 + e][ds * 32 + (ln & 31)];
                size_t ga = ((((size_t)bidx * 128 + (t0 >> 4) + kcl) * 4 + ds) * 64 + ln) * 8;
                *(f16x8*)&Va[ga] = vv;
            }
        }
    }
}

// ---------------------------------------------------------------------------
// Kernel 2: MFMA flash attention — BARRIER-FREE (no K/V LDS staging).
// Transposed softmax (S^T = K Q^T), 32x32x16, Q-tile 128 (4 waves x 32 q),
// K-tile 64, chunked split-K (<=8 k-tiles/block, 40x8 grid, big chunks first).
// All K/V/Q fragments are coalesced loads from pre-swizzled global arrays;
// only P round-trips through (same-wave) LDS.
// ---------------------------------------------------------------------------
__global__ __launch_bounds__(256)
void attn_kernel(const _Float16* __restrict__ Qb,
                 const _Float16* __restrict__ Ka,
                 const _Float16* __restrict__ Va,
                 _Float16* __restrict__ opart,
                 float* __restrict__ mpart,
                 float* __restrict__ lpart)
{
    const int b  = blockIdx.y;
    const int v_ = 39 - blockIdx.x;         // ascending-work table, reversed
    int xt, c;
    if (v_ < 4)       { xt = v_;                  c = 0; }
    else if (v_ < 12) { xt = 4 + ((v_ - 4) >> 1); c = (v_ - 4) & 1; }
    else if (v_ < 24) { xt = 8 + (v_ - 12) / 3;   c = (v_ - 12) % 3; }
    else              { xt = 12 + ((v_ - 24) >> 2); c = (v_ - 24) & 3; }
    const int q0 = xt * 128;
    const int nt = 2 * xt + 2;              // causal 64-key tiles
    const int kt_begin = c * 8;
    const int kt_end   = (kt_begin + 8 < nt) ? (kt_begin + 8) : nt;

    const int tid  = threadIdx.x;
    const int wave = tid >> 6;
    const int lane = tid & 63;
    const int half = lane >> 5;
    const int col  = lane & 31;

    __shared__ _Float16 Ps[4][32][72];      // [wave][q][key] — same-wave only

    const int qg = q0 + wave * 32 + col;    // this lane's query
    f16x8 qb[8];
#pragma unroll
    for (int kc = 0; kc < 8; kc++)
        qb[kc] = *(const f16x8*)&Qb[((((size_t)b * 64 + xt * 4 + wave) * 8 + kc) * 64 + lane) * 8];

    f32x16 Of[4];
#pragma unroll
    for (int t = 0; t < 4; t++) Of[t] = (f32x16)0.f;
    float m_ = -1e30f, l_ = 0.f;

    for (int kt = kt_begin; kt < kt_end; kt++) {
        const int kb0 = kt * 64;

        // ---- S^T = K Q^T : rows = keys, cols = queries ----
        f32x16 sf[2];
#pragma unroll
        for (int g = 0; g < 2; g++) {
            sf[g] = (f32x16)0.f;
#pragma unroll
            for (int kc = 0; kc < 8; kc++) {
                f16x8 kf = *(const f16x8*)&Ka[((((size_t)b * 64 + 2 * kt + g) * 8 + kc) * 64 + lane) * 8];
                sf[g] = __builtin_amdgcn_mfma_f32_32x32x16_f16(kf, qb[kc], sf[g], 0, 0, 0);
            }
        }

        // ---- softmax: 32 key-scores in-lane, one shfl step (xor 32) ----
        const bool diag = (kt >= 2 * xt);
        float mloc = -1e30f;
#pragma unroll
        for (int g = 0; g < 2; g++)
#pragma unroll
            for (int rg = 0; rg < 16; rg++) {
                int key = kb0 + g * 32 + (rg & 3) + 8 * (rg >> 2) + 4 * half;
                float val = sf[g][rg];
                val = (!diag || key <= qg) ? val : -1e30f;
                sf[g][rg] = val;
                mloc = fmaxf(mloc, val);
            }
        mloc = fmaxf(mloc, __shfl_xor(mloc, 32));
        float mnew  = fmaxf(m_, mloc);
        float alpha = __builtin_amdgcn_exp2f(m_ - mnew);
        float ps = 0.f;
#pragma unroll
        for (int g = 0; g < 2; g++) {
#pragma unroll
            for (int rc = 0; rc < 4; rc++) {
                f16x4 p4;
#pragma unroll
                for (int rr = 0; rr < 4; rr++) {
                    float p = __builtin_amdgcn_exp2f(sf[g][4 * rc + rr] - mnew);
                    ps += p;
                    p4[rr] = (_Float16)p;
                }
                *(f16x4*)&Ps[wave][col][g * 32 + 8 * rc + 4 * half] = p4;
            }
        }
        ps += __shfl_xor(ps, 32);
        l_ = l_ * alpha + ps;
        m_ = mnew;
#pragma unroll
        for (int t = 0; t < 4; t++) Of[t] *= alpha;

        // ---- O^T += V^T P^T (P via same-wave LDS round-trip, in-order DS) ----
        f16x8 pb[4];
#pragma unroll
        for (int kc = 0; kc < 4; kc++)
            pb[kc] = *(f16x8*)&Ps[wave][col][kc * 16 + half * 8];
#pragma unroll
        for (int t = 0; t < 4; t++) {
#pragma unroll
            for (int kcl = 0; kcl < 4; kcl++) {
                f16x8 vf = *(const f16x8*)&Va[((((size_t)b * 128 + kt * 4 + kcl) * 4 + t) * 64 + lane) * 8];
                Of[t] = __builtin_amdgcn_mfma_f32_32x32x16_f16(vf, pb[kcl], Of[t], 0, 0, 0);
            }
        }
    }

    // ---- partial store (f16 unnormalized O^T -> [q][d], f32 m/l) ----
    const int slot = (b * 16 + xt) * 4 + c;
    _Float16* op = opart + ((size_t)slot * 128 + wave * 32 + col) * DD;
#pragma unroll
    for (int t = 0; t < 4; t++) {
#pragma unroll
        for (int rc = 0; rc < 4; rc++) {
            f16x4 o4 = { (_Float16)Of[t][4 * rc + 0], (_Float16)Of[t][4 * rc + 1],
                         (_Float16)Of[t][4 * rc + 2], (_Float16)Of[t][4 * rc + 3] };
            *(f16x4*)&op[t * 32 + 8 * rc + 4 * half] = o4;
        }
    }
    if (half == 0) {
        mpart[slot * 128 + wave * 32 + col] = m_;
        lpart[slot * 128 + wave * 32 + col] = l_;
    }
}

// ---------------------------------------------------------------------------
// Kernel 3: combine up to 4 split-K partials per query row.
// ---------------------------------------------------------------------------
__global__ __launch_bounds__(256)
void combine_kernel(const _Float16* __restrict__ opart,
                    const float* __restrict__ mpart,
                    const float* __restrict__ lpart,
                    float* __restrict__ out)
{
    int gid = blockIdx.x * 256 + threadIdx.x;   // 0..2M-1
    int d   = gid & 127;
    int t   = gid >> 7;                         // 0..16383
    int b   = t >> 11;
    int tl  = t & (TT - 1);
    int xt  = tl >> 7;
    int rl  = tl & 127;
    int np  = (2 * xt + 2 + 7) >> 3;
    int sb  = (b * 16 + xt) * 4;

    float mm = -1e30f;
    for (int j = 0; j < np; j++)
        mm = fmaxf(mm, mpart[(sb + j) * 128 + rl]);
    float acc = 0.f, den = 0.f;
    for (int j = 0; j < np; j++) {
        float w = __builtin_amdgcn_exp2f(mpart[(sb + j) * 128 + rl] - mm);
        den += w * lpart[(sb + j) * 128 + rl];
        acc += w * (float)opart[((size_t)(sb + j) * 128 + rl) * DD + d];
    }
    out[gid] = acc / den;
}

extern "C" void kernel_launch(void* const* d_in, const int* in_sizes, int n_in,
                              void* d_out, int out_size, void* d_ws, size_t ws_size,
                              hipStream_t stream)
{
    const float* x  = (const float*)d_in[0];
    const float* Wq = (const float*)d_in[1];
    const float* Wk = (const float*)d_in[2];
    const float* Wv = (const float*)d_in[3];
    float* out = (float*)d_out;

    const size_t NTOK = (size_t)BB * TT;        // 16384
    _Float16* Qb = (_Float16*)d_ws;             // 4 MB
    _Float16* Ka = Qb + NTOK * DD;              // 4 MB
    _Float16* Va = Ka + NTOK * DD;              // 4 MB
    _Float16* Wb = Va + NTOK * DD;              // 0.75 MB
    _Float16* opart = Wb + (size_t)384 * EE;    // 16 MB (512 slots x 128 x 128)
    float* mp = (float*)(opart + (size_t)512 * 128 * DD);   // 256 KB
    float* lp = mp + 512 * 128;                 // 256 KB

    wt_prep_kernel<<<dim3(192), dim3(256), 0, stream>>>(Wq, Wk, Wv, Wb);
    proj_rope_kernel<<<dim3(256), dim3(512), 0, stream>>>(x, Wb, Qb, Ka, Va);
    attn_kernel<<<dim3(40, BB), dim3(256), 0, stream>>>(Qb, Ka, Va, opart, mp, lp);
    combine_kernel<<<dim3((int)(NTOK * DD / 256)), dim3(256), 0, stream>>>(opart, mp, lp, out);
}

// Round 7
// 164.811 us; speedup vs baseline: 1.1800x; 1.1800x over previous
//
#include <hip/hip_runtime.h>
#include <math.h>

#define BB 8
#define TT 2048
#define EE 1024
#define DD 128

typedef _Float16 f16x8 __attribute__((ext_vector_type(8)));
typedef _Float16 f16x4 __attribute__((ext_vector_type(4)));
typedef float    f32x4 __attribute__((ext_vector_type(4)));
typedef float    f32x16 __attribute__((ext_vector_type(16)));

// scale (128^-0.5) * log2(e): folded into q so softmax runs in exp2 domain
#define QSCALE 0.12752406f

// ---------------------------------------------------------------------------
// Fragment layouts (32x32x16 MFMA, m74/m101 verified):
//   A[m = lane&31][k = (lane>>5)*8 + j]   (f16x8 per lane)
//   B[k = (lane>>5)*8 + j][n = lane&31]
//   C/D row = (rg&3) + 8*(rg>>2) + 4*(lane>>5), col = lane&31
// Frag-order global arrays: frag_id*512 + lane*8 + j -> 1KB coalesced blobs.
// ---------------------------------------------------------------------------

// Kernel 0: Wb[(kc*12 + ns)*512 + lane*8 + j] = W[k=kc*16+(lane>>5)*8+j][n]
__global__ __launch_bounds__(256)
void wt_prep_kernel(const float* __restrict__ Wq,
                    const float* __restrict__ Wk,
                    const float* __restrict__ Wv,
                    _Float16* __restrict__ Wb)
{
    int gid = blockIdx.x * 256 + threadIdx.x;   // 0..49151
    int kc  = gid / 768;
    int rem = gid - kc * 768;
    int ns  = rem >> 6;
    int ln  = rem & 63;
    int n   = ns * 32 + (ln & 31);
    int k0  = kc * 16 + (ln >> 5) * 8;
    const float* __restrict__ W = (n < 128) ? Wq : (n < 256) ? Wk : Wv;
    int nl = n & 127;
    f16x8 w;
#pragma unroll
    for (int j = 0; j < 8; j++)
        w[j] = (_Float16)W[(size_t)(k0 + j) * DD + nl];
    *(f16x8*)&Wb[(size_t)gid * 8] = w;
}

// ---------------------------------------------------------------------------
// Kernel 1: fused QKV projection.  M=64, N=384, BK=64 (16 iters), grid 256,
// 512 thr = 8 waves (wave_m{0,1} x wave_n{0..3}, 3 n-subtiles each).
// X: LDS double-buffered in A-frag blob order (coalesced f32 stage + cvt),
//    ONE barrier per iter, 2-deep register prefetch.
// W: direct frag-order loads from L2-resident Wb (no LDS).
// Outputs in frag order: Qb/Ka (B/A-frag), Va (V^T A-frag).
// ---------------------------------------------------------------------------
__global__ __launch_bounds__(512)
void proj_rope_kernel(const float* __restrict__ x,
                      const _Float16* __restrict__ Wb,
                      _Float16* __restrict__ Qb,
                      _Float16* __restrict__ Ka,
                      _Float16* __restrict__ Va)
{
    const int r0   = blockIdx.x * 64;       // 64 | 2048: never straddles batch
    const int tid  = threadIdx.x;
    const int wave = tid >> 6;
    const int lane = tid & 63;
    const int half = lane >> 5;
    const int col  = lane & 31;
    const int wave_m = wave & 1;
    const int wave_n = wave >> 1;

    __shared__ _Float16 Xb[2][4096];        // 8 blobs (4 kc x 2 sm) x 512 f16
    __shared__ _Float16 Out[64][136];       // epilogue transpose buffer

    f32x16 acc[3];
#pragma unroll
    for (int s = 0; s < 3; s++) acc[s] = (f32x16)0.f;

    // staging map: thread -> (row sr, f16-col c in {sc, sc+32})
    const int sr = tid >> 3;                // 0..63
    const int sc = (tid & 7) * 4;           // 0..28
    const float* __restrict__ xp = &x[(size_t)(r0 + sr) * EE + sc];
    // blob index: ((c>>4)*2 + sm)*512 + ((sr&31) + 32*((c>>3)&1))*8 + (c&7)
    const int sm = sr >> 5, rr = sr & 31;
    const int w0 = (((sc      >> 4) * 2 + sm) << 9) + ((rr + 32 * ((sc       >> 3) & 1)) << 3) + (sc & 7);
    const int w1 = ((((sc+32) >> 4) * 2 + sm) << 9) + ((rr + 32 * (((sc+32)  >> 3) & 1)) << 3) + (sc & 7);

    float4 pa0 = *(const float4*)(xp);
    float4 pa1 = *(const float4*)(xp + 32);
    {   // pre-loop commit of iter 0 (no readers yet)
        f16x4 h0 = { (_Float16)pa0.x, (_Float16)pa0.y, (_Float16)pa0.z, (_Float16)pa0.w };
        f16x4 h1 = { (_Float16)pa1.x, (_Float16)pa1.y, (_Float16)pa1.z, (_Float16)pa1.w };
        *(f16x4*)&Xb[0][w0] = h0;
        *(f16x4*)&Xb[0][w1] = h1;
    }
    float4 na0 = *(const float4*)(xp + 64);
    float4 na1 = *(const float4*)(xp + 96);

    for (int it = 0; it < 16; it++) {
        const int buf = it & 1;
        __syncthreads();                    // Xb[buf] commits visible
        // compute: A from LDS blobs, B from global frag-order Wb
#pragma unroll
        for (int kc = 0; kc < 4; kc++) {
            f16x8 a = *(f16x8*)&Xb[buf][((kc * 2 + wave_m) << 9) + lane * 8];
#pragma unroll
            for (int s = 0; s < 3; s++) {
                f16x8 b = *(const f16x8*)&Wb[((size_t)(it * 4 + kc) * 12 + wave_n * 3 + s) * 512 + lane * 8];
                acc[s] = __builtin_amdgcn_mfma_f32_32x32x16_f16(a, b, acc[s], 0, 0, 0);
            }
        }
        // commit iter it+1 into the other buffer (its old readers done at barrier)
        if (it + 1 < 16) {
            f16x4 h0 = { (_Float16)na0.x, (_Float16)na0.y, (_Float16)na0.z, (_Float16)na0.w };
            f16x4 h1 = { (_Float16)na1.x, (_Float16)na1.y, (_Float16)na1.z, (_Float16)na1.w };
            *(f16x4*)&Xb[buf ^ 1][w0] = h0;
            *(f16x4*)&Xb[buf ^ 1][w1] = h1;
        }
        // issue iter it+2 loads (a full iteration to cover HBM latency)
        if (it + 2 < 16) {
            na0 = *(const float4*)(xp + (it + 2) * 64);
            na1 = *(const float4*)(xp + (it + 2) * 64 + 32);
        }
    }

    // ---- epilogue: RoPE + frag-layout stores via Out round-trip ----
    const int bidx = r0 >> 11;
    const int t0   = r0 & (TT - 1);

    for (int p = 0; p < 3; p++) {
        __syncthreads();
#pragma unroll
        for (int s = 0; s < 3; s++) {
            int gs = wave_n * 3 + s;        // 0..11 global 32-col subtile
            if ((gs >> 2) != p) continue;
            int dcol = (gs & 3) * 32 + col; // 0..127 within matrix p
            float f = 0.f;
            if (p < 2)
                f = __powf(10000.0f, -(float)(dcol & ~1) * (1.0f / 128.0f));
#pragma unroll
            for (int rg = 0; rg < 16; rg++) {
                int mrow = wave_m * 32 + (rg & 3) + 8 * (rg >> 2) + 4 * half;
                float av = acc[s][rg];
                float res;
                if (p < 2) {
                    float ap = __shfl_xor(av, 1);   // RoPE pair partner (dcol^1)
                    float sa, ca;
                    __sincosf((float)(t0 + mrow) * f, &sa, &ca);
                    res = av * ca + ap * ((dcol & 1) ? sa : -sa);
                    if (p == 0) res *= QSCALE;
                } else {
                    res = av;
                }
                Out[mrow][dcol] = (_Float16)res;
            }
        }
        __syncthreads();
        if (p < 2) {
            _Float16* __restrict__ dst = (p == 0) ? Qb : Ka;
#pragma unroll
            for (int jj = 0; jj < 2; jj++) {
                int cid = tid + 512 * jj;   // 0..1023 = 2 subtiles x 8 kc x 64 lanes
                int sl = cid >> 9, kc = (cid >> 6) & 7, ln = cid & 63;
                f16x8 v8 = *(f16x8*)&Out[sl * 32 + (ln & 31)][kc * 16 + (ln >> 5) * 8];
                size_t ga = ((((size_t)bidx * 64 + (t0 >> 5) + sl) * 8 + kc) * 64 + ln) * 8;
                *(f16x8*)&dst[ga] = v8;
            }
        } else {
#pragma unroll
            for (int jj = 0; jj < 2; jj++) {
                int cid = tid + 512 * jj;   // 0..1023 = 4 key-chunks x 4 ds x 64 lanes
                int kcl = cid >> 8, ds = (cid >> 6) & 3, ln = cid & 63;
                f16x8 vv;
#pragma unroll
                for (int e = 0; e < 8; e++)
                    vv[e] = Out[kcl * 16 + (ln >> 5) * 8 + e][ds * 32 + (ln & 31)];
                size_t ga = ((((size_t)bidx * 128 + (t0 >> 4) + kcl) * 4 + ds) * 64 + ln) * 8;
                *(f16x8*)&Va[ga] = vv;
            }
        }
    }
}

// ---------------------------------------------------------------------------
// Kernel 2: MFMA flash attention, transposed softmax, K/V staged in LDS as
// contiguous frag blobs (tile = one 16KB memcpy), reg-prefetch across the
// 2-barrier iter.  Q-tile 128 (4 waves), K-tile 64, chunked split-K.
// ---------------------------------------------------------------------------
__global__ __launch_bounds__(256)
void attn_kernel(const _Float16* __restrict__ Qb,
                 const _Float16* __restrict__ Ka,
                 const _Float16* __restrict__ Va,
                 _Float16* __restrict__ opart,
                 float* __restrict__ mpart,
                 float* __restrict__ lpart)
{
    const int b  = blockIdx.y;
    const int v_ = 39 - blockIdx.x;         // ascending-work table, reversed
    int xt, c;
    if (v_ < 4)       { xt = v_;                  c = 0; }
    else if (v_ < 12) { xt = 4 + ((v_ - 4) >> 1); c = (v_ - 4) & 1; }
    else if (v_ < 24) { xt = 8 + (v_ - 12) / 3;   c = (v_ - 12) % 3; }
    else              { xt = 12 + ((v_ - 24) >> 2); c = (v_ - 24) & 3; }
    const int q0 = xt * 128;
    const int nt = 2 * xt + 2;              // causal 64-key tiles
    const int kt_begin = c * 8;
    const int kt_end   = (kt_begin + 8 < nt) ? (kt_begin + 8) : nt;

    const int tid  = threadIdx.x;
    const int wave = tid >> 6;
    const int lane = tid & 63;
    const int half = lane >> 5;
    const int col  = lane & 31;

    __shared__ _Float16 Kb[8192];           // 16 blobs (g*8+kc) x 512 f16
    __shared__ _Float16 Vb[8192];           // 16 blobs (kcl*4+ds) x 512 f16
    __shared__ _Float16 Ps[4][32][72];      // [wave][q][key] — same-wave only

    // per-b bases; tile kt = 16KB contiguous at +kt*8192 in both arrays
    const _Float16* __restrict__ kst = Ka + (size_t)b * 64 * 4096;
    const _Float16* __restrict__ vst = Va + (size_t)b * 128 * 2048;

    const int qg = q0 + wave * 32 + col;    // this lane's query
    f16x8 qb[8];
#pragma unroll
    for (int kc = 0; kc < 8; kc++)
        qb[kc] = *(const f16x8*)&Qb[((((size_t)b * 64 + xt * 4 + wave) * 8 + kc) * 64 + lane) * 8];

    f32x16 Of[4];
#pragma unroll
    for (int t = 0; t < 4; t++) Of[t] = (f32x16)0.f;
    float m_ = -1e30f, l_ = 0.f;

    // register prefetch of first tile (coalesced 16KB memcpys)
    f16x8 kr[4], vr[4];
    {
        const _Float16* kp = kst + (size_t)kt_begin * 8192;
        const _Float16* vp = vst + (size_t)kt_begin * 8192;
#pragma unroll
        for (int i = 0; i < 4; i++) kr[i] = *(const f16x8*)&kp[(tid + 256 * i) * 8];
#pragma unroll
        for (int i = 0; i < 4; i++) vr[i] = *(const f16x8*)&vp[(tid + 256 * i) * 8];
    }

    for (int kt = kt_begin; kt < kt_end; kt++) {
        const int kb0 = kt * 64;
        __syncthreads();                    // prev compute done reading LDS
#pragma unroll
        for (int i = 0; i < 4; i++) *(f16x8*)&Kb[(tid + 256 * i) * 8] = kr[i];
#pragma unroll
        for (int i = 0; i < 4; i++) *(f16x8*)&Vb[(tid + 256 * i) * 8] = vr[i];
        __syncthreads();                    // staging visible
        if (kt + 1 < kt_end) {              // issue next-tile loads now
            const _Float16* kp = kst + (size_t)(kt + 1) * 8192;
            const _Float16* vp = vst + (size_t)(kt + 1) * 8192;
#pragma unroll
            for (int i = 0; i < 4; i++) kr[i] = *(const f16x8*)&kp[(tid + 256 * i) * 8];
#pragma unroll
            for (int i = 0; i < 4; i++) vr[i] = *(const f16x8*)&vp[(tid + 256 * i) * 8];
        }

        // ---- S^T = K Q^T : rows = keys, cols = queries ----
        f32x16 sf[2];
#pragma unroll
        for (int g = 0; g < 2; g++) {
            sf[g] = (f32x16)0.f;
#pragma unroll
            for (int kc = 0; kc < 8; kc++) {
                f16x8 kf = *(f16x8*)&Kb[((g * 8 + kc) * 64 + lane) * 8];
                sf[g] = __builtin_amdgcn_mfma_f32_32x32x16_f16(kf, qb[kc], sf[g], 0, 0, 0);
            }
        }

        // ---- softmax: 32 key-scores in-lane, one shfl step (xor 32) ----
        const bool diag = (kt >= 2 * xt);
        float mloc = -1e30f;
#pragma unroll
        for (int g = 0; g < 2; g++)
#pragma unroll
            for (int rg = 0; rg < 16; rg++) {
                int key = kb0 + g * 32 + (rg & 3) + 8 * (rg >> 2) + 4 * half;
                float val = sf[g][rg];
                val = (!diag || key <= qg) ? val : -1e30f;
                sf[g][rg] = val;
                mloc = fmaxf(mloc, val);
            }
        mloc = fmaxf(mloc, __shfl_xor(mloc, 32));
        float mnew  = fmaxf(m_, mloc);
        float alpha = __builtin_amdgcn_exp2f(m_ - mnew);
        float ps = 0.f;
#pragma unroll
        for (int g = 0; g < 2; g++) {
#pragma unroll
            for (int rc = 0; rc < 4; rc++) {
                f16x4 p4;
#pragma unroll
                for (int rr = 0; rr < 4; rr++) {
                    float p = __builtin_amdgcn_exp2f(sf[g][4 * rc + rr] - mnew);
                    ps += p;
                    p4[rr] = (_Float16)p;
                }
                *(f16x4*)&Ps[wave][col][g * 32 + 8 * rc + 4 * half] = p4;
            }
        }
        ps += __shfl_xor(ps, 32);
        l_ = l_ * alpha + ps;
        m_ = mnew;
#pragma unroll
        for (int t = 0; t < 4; t++) Of[t] *= alpha;

        // ---- O^T += V^T P^T (P via same-wave LDS round-trip) ----
        f16x8 pb[4];
#pragma unroll
        for (int kc = 0; kc < 4; kc++)
            pb[kc] = *(f16x8*)&Ps[wave][col][kc * 16 + half * 8];
#pragma unroll
        for (int t = 0; t < 4; t++) {
#pragma unroll
            for (int kcl = 0; kcl < 4; kcl++) {
                f16x8 vf = *(f16x8*)&Vb[((kcl * 4 + t) * 64 + lane) * 8];
                Of[t] = __builtin_amdgcn_mfma_f32_32x32x16_f16(vf, pb[kcl], Of[t], 0, 0, 0);
            }
        }
    }

    // ---- partial store (f16 unnormalized O^T -> [q][d], f32 m/l) ----
    const int slot = (b * 16 + xt) * 4 + c;
    _Float16* op = opart + ((size_t)slot * 128 + wave * 32 + col) * DD;
#pragma unroll
    for (int t = 0; t < 4; t++) {
#pragma unroll
        for (int rc = 0; rc < 4; rc++) {
            f16x4 o4 = { (_Float16)Of[t][4 * rc + 0], (_Float16)Of[t][4 * rc + 1],
                         (_Float16)Of[t][4 * rc + 2], (_Float16)Of[t][4 * rc + 3] };
            *(f16x4*)&op[t * 32 + 8 * rc + 4 * half] = o4;
        }
    }
    if (half == 0) {
        mpart[slot * 128 + wave * 32 + col] = m_;
        lpart[slot * 128 + wave * 32 + col] = l_;
    }
}

// ---------------------------------------------------------------------------
// Kernel 3: combine up to 4 split-K partials per query row.
// ---------------------------------------------------------------------------
__global__ __launch_bounds__(256)
void combine_kernel(const _Float16* __restrict__ opart,
                    const float* __restrict__ mpart,
                    const float* __restrict__ lpart,
                    float* __restrict__ out)
{
    int gid = blockIdx.x * 256 + threadIdx.x;   // 0..2M-1
    int d   = gid & 127;
    int t   = gid >> 7;                         // 0..16383
    int b   = t >> 11;
    int tl  = t & (TT - 1);
    int xt  = tl >> 7;
    int rl  = tl & 127;
    int np  = (2 * xt + 2 + 7) >> 3;
    int sb  = (b * 16 + xt) * 4;

    float mm = -1e30f;
    for (int j = 0; j < np; j++)
        mm = fmaxf(mm, mpart[(sb + j) * 128 + rl]);
    float acc = 0.f, den = 0.f;
    for (int j = 0; j < np; j++) {
        float w = __builtin_amdgcn_exp2f(mpart[(sb + j) * 128 + rl] - mm);
        den += w * lpart[(sb + j) * 128 + rl];
        acc += w * (float)opart[((size_t)(sb + j) * 128 + rl) * DD + d];
    }
    out[gid] = acc / den;
}

extern "C" void kernel_launch(void* const* d_in, const int* in_sizes, int n_in,
                              void* d_out, int out_size, void* d_ws, size_t ws_size,
                              hipStream_t stream)
{
    const float* x  = (const float*)d_in[0];
    const float* Wq = (const float*)d_in[1];
    const float* Wk = (const float*)d_in[2];
    const float* Wv = (const float*)d_in[3];
    float* out = (float*)d_out;

    const size_t NTOK = (size_t)BB * TT;        // 16384
    _Float16* Qb = (_Float16*)d_ws;             // 4 MB
    _Float16* Ka = Qb + NTOK * DD;              // 4 MB
    _Float16* Va = Ka + NTOK * DD;              // 4 MB
    _Float16* Wb = Va + NTOK * DD;              // 0.75 MB
    _Float16* opart = Wb + (size_t)384 * EE;    // 16 MB (512 slots x 128 x 128)
    float* mp = (float*)(opart + (size_t)512 * 128 * DD);   // 256 KB
    float* lp = mp + 512 * 128;                 // 256 KB

    wt_prep_kernel<<<dim3(192), dim3(256), 0, stream>>>(Wq, Wk, Wv, Wb);
    proj_rope_kernel<<<dim3(256), dim3(512), 0, stream>>>(x, Wb, Qb, Ka, Va);
    attn_kernel<<<dim3(40, BB), dim3(256), 0, stream>>>(Qb, Ka, Va, opart, mp, lp);
    combine_kernel<<<dim3((int)(NTOK * DD / 256)), dim3(256), 0, stream>>>(opart, mp, lp, out);
}